// Round 10
// baseline (185.625 us; speedup 1.0000x reference)
//
#include <hip/hip_runtime.h>

// GPT2 attention w/ soft-threshold pruning — round 10.
// vs r9: (1) de-stride attention operand layouts: Q,K head-major [h][2048][64]
// (128B row stride) and V^T padded [1024][2080] (4160B stride) — r9's 2KB/4KB
// power-of-2 strides serialize L2 banks on every fragment load (8kcy/iter
// measured). (2) attn back to r8's 2-wave split-K. (3) precision-tiered GEMMs:
// Q = split x split (3 MFMA); K,V = plain bf16 (1 MFMA; their bf16 rounding
// already dominates their error); GEMM2 plain-A. absmax est ~0.020 (<0.029).

#define S_LEN 2048
#define DM    1024
#define NH    16
#define HD    64
#define SLOPE 10.0f
#define CMASK -10000.0f
#define SP    2080      // padded V^T row stride (shorts)

typedef short s16x4 __attribute__((ext_vector_type(4)));
typedef short s16x8 __attribute__((ext_vector_type(8)));
typedef float f32x4 __attribute__((ext_vector_type(4)));

#define MFMA16(a,b,c) __builtin_amdgcn_mfma_f32_16x16x32_bf16(a,b,c,0,0,0)
#define GLDS16(g,l) __builtin_amdgcn_global_load_lds( \
    (const __attribute__((address_space(1))) void*)(g), \
    (__attribute__((address_space(3))) void*)(l), 16, 0, 0)

__device__ __forceinline__ short f2bf(float f){
    unsigned u = __float_as_uint(f);
    u += 0x7fffu + ((u >> 16) & 1u);          // RNE
    return (short)(u >> 16);
}
__device__ __forceinline__ float bf2f(short x){
    return __uint_as_float(((unsigned)(unsigned short)x) << 16);
}
struct bfpair { short hi, lo; };
__device__ __forceinline__ bfpair split_bf(float x){
    bfpair r; r.hi = f2bf(x);
    r.lo = f2bf(x - bf2f(r.hi));
    return r;
}

// ---- GEMM staging: [ROWS][64] bf16 tile via global_load_lds, XOR-swizzled ----
template<int ROWS, int THREADS>
__device__ __forceinline__ void stage_tile(const short* gbase, int rstride,
                                           short* lds, int tid){
#pragma unroll
    for (int it = 0; it < ROWS*8/THREADS; ++it){
        int s = it*THREADS + tid;
        int row = s >> 3, grp = s & 7;
        const short* src = gbase + (size_t)row*rstride + ((grp ^ (row & 7)) << 3);
        GLDS16(src, lds + (size_t)s*8);
    }
}
__device__ __forceinline__ s16x8 frag(const short* lds, int row, int kg){
    return *(const s16x8*)&lds[row*64 + ((kg ^ (row & 7)) << 3)];
}

// ---------------- GEMM 128x128, BK=64, 4 waves (2x2 of 64x64) ----------------
// SPLIT: 3-MFMA split x split. OUT: 0 = Q split-store head-major (o0=hi,o1=lo)
// 1 = K bf16 head-major; 2 = V bf16 [s][1024]; 3 = f32 + bias (proj out).
template<bool SPLIT, int OUT>
__global__ __launch_bounds__(256)
void gemm_s(const short* __restrict__ Ahg, const short* __restrict__ Alg,
            const short* __restrict__ Bhg, const short* __restrict__ Blg,
            const float* __restrict__ bias,
            short* __restrict__ o0, short* __restrict__ o1,
            float* __restrict__ of)
{
    __shared__ __align__(16) short Ah_s[128*64];
    __shared__ __align__(16) short Bh_s[128*64];
    __shared__ __align__(16) short Al_s[SPLIT ? 128*64 : 8];
    __shared__ __align__(16) short Bl_s[SPLIT ? 128*64 : 8];

    const int tid = threadIdx.x, lane = tid & 63, wid = tid >> 6;
    const int lr = lane & 15, lg = lane >> 4;
    const int brow = blockIdx.y*128, bcol = blockIdx.x*128;
    const int wm = (wid >> 1)*64, wn = (wid & 1)*64;

    f32x4 acc[4][4];
#pragma unroll
    for (int m = 0; m < 4; ++m)
#pragma unroll
        for (int n = 0; n < 4; ++n) acc[m][n] = (f32x4){0.f,0.f,0.f,0.f};

    for (int k0 = 0; k0 < DM; k0 += 64){
        stage_tile<128,256>(Ahg + (size_t)brow*DM + k0, DM, Ah_s, tid);
        stage_tile<128,256>(Bhg + (size_t)bcol*DM + k0, DM, Bh_s, tid);
        if constexpr (SPLIT){
            stage_tile<128,256>(Alg + (size_t)brow*DM + k0, DM, Al_s, tid);
            stage_tile<128,256>(Blg + (size_t)bcol*DM + k0, DM, Bl_s, tid);
        }
        __syncthreads();
#pragma unroll
        for (int kc = 0; kc < 2; ++kc){
            s16x8 ah[4], al[4], bh[4], bl[4];
#pragma unroll
            for (int m = 0; m < 4; ++m){
                ah[m] = frag(Ah_s, wm + m*16 + lr, kc*4 + lg);
                if constexpr (SPLIT) al[m] = frag(Al_s, wm + m*16 + lr, kc*4 + lg);
            }
#pragma unroll
            for (int n = 0; n < 4; ++n){
                bh[n] = frag(Bh_s, wn + n*16 + lr, kc*4 + lg);
                if constexpr (SPLIT) bl[n] = frag(Bl_s, wn + n*16 + lr, kc*4 + lg);
            }
#pragma unroll
            for (int m = 0; m < 4; ++m)
#pragma unroll
                for (int n = 0; n < 4; ++n){
                    acc[m][n] = MFMA16(ah[m], bh[n], acc[m][n]);
                    if constexpr (SPLIT){
                        acc[m][n] = MFMA16(ah[m], bl[n], acc[m][n]);
                        acc[m][n] = MFMA16(al[m], bh[n], acc[m][n]);
                    }
                }
        }
        __syncthreads();
    }

#pragma unroll
    for (int m = 0; m < 4; ++m)
#pragma unroll
        for (int n = 0; n < 4; ++n){
            int row  = brow + wm + m*16 + lg*4;
            int gcol = bcol + wn + n*16 + lr;
            float bv = bias[gcol];
            int h0 = gcol >> 6, d = gcol & 63;
#pragma unroll
            for (int v = 0; v < 4; ++v){
                float val = acc[m][n][v] + bv;
                if constexpr (OUT == 0){
                    bfpair p = split_bf(val);
                    size_t o = ((size_t)h0*S_LEN + row + v)*HD + d;
                    o0[o] = p.hi; o1[o] = p.lo;
                } else if constexpr (OUT == 1){
                    o0[((size_t)h0*S_LEN + row + v)*HD + d] = f2bf(val);
                } else if constexpr (OUT == 2){
                    o0[(size_t)(row + v)*DM + gcol] = f2bf(val);
                } else {
                    of[(size_t)(row + v)*DM + gcol] = val;
                }
            }
        }
}

// ---------------- prep kernels ----------------
__global__ __launch_bounds__(256)
void split_f32(const float* __restrict__ x, short* __restrict__ h,
               short* __restrict__ l, int n4)
{
    int i = blockIdx.x*256 + threadIdx.x;
    if (i >= n4) return;
    float4 v = *(const float4*)&x[(size_t)i*4];
    bfpair a = split_bf(v.x), b = split_bf(v.y), c = split_bf(v.z), d = split_bf(v.w);
    s16x4 hv, lv;
    hv.x = a.hi; hv.y = b.hi; hv.z = c.hi; hv.w = d.hi;
    lv.x = a.lo; lv.y = b.lo; lv.z = c.lo; lv.w = d.lo;
    *(s16x4*)&h[(size_t)i*4] = hv;
    *(s16x4*)&l[(size_t)i*4] = lv;
}

template<bool SPL>
__global__ __launch_bounds__(256)
void wtrans(const float* __restrict__ W, int N, short* __restrict__ Th,
            short* __restrict__ Tl)
{
    __shared__ float t[64][65];
    const int tid = threadIdx.x;
    const int tn = blockIdx.x*64, tk = blockIdx.y*64;
#pragma unroll
    for (int it = 0; it < 4; ++it){
        int idx = tid + it*256;
        int r = idx >> 4, c4 = (idx & 15)*4;
        float4 v = *(const float4*)&W[(size_t)(tk + r)*N + tn + c4];
        t[r][c4] = v.x; t[r][c4+1] = v.y; t[r][c4+2] = v.z; t[r][c4+3] = v.w;
    }
    __syncthreads();
#pragma unroll
    for (int it = 0; it < 4; ++it){
        int idx = tid + it*256;
        int n = idx >> 4, c4 = (idx & 15)*4;
        s16x4 hv, lv;
#pragma unroll
        for (int j = 0; j < 4; ++j){
            bfpair p = split_bf(t[c4+j][n]);
            hv[j] = p.hi; lv[j] = p.lo;
        }
        *(s16x4*)&Th[(size_t)(tn + n)*DM + tk + c4] = hv;
        if constexpr (SPL) *(s16x4*)&Tl[(size_t)(tn + n)*DM + tk + c4] = lv;
    }
}

// V [2048][1024] bf16 -> V^T [1024][SP] bf16 (padded stride kills aliasing)
__global__ __launch_bounds__(256)
void vtrans(const short* __restrict__ Vb, short* __restrict__ Vt)
{
    __shared__ short t[64][66];
    const int tid = threadIdx.x;
    const int td = blockIdx.x*64, ts = blockIdx.y*64;
#pragma unroll
    for (int it = 0; it < 4; ++it){
        int idx = tid + it*256;
        int r = idx >> 4, c4 = (idx & 15)*4;
        s16x4 v = *(const s16x4*)&Vb[(size_t)(ts + r)*DM + td + c4];
        t[r][c4] = v.x; t[r][c4+1] = v.y; t[r][c4+2] = v.z; t[r][c4+3] = v.w;
    }
    __syncthreads();
#pragma unroll
    for (int it = 0; it < 4; ++it){
        int idx = tid + it*256;
        int n = idx >> 4, c4 = (idx & 15)*4;
        s16x4 o;
#pragma unroll
        for (int j = 0; j < 4; ++j) o[j] = t[c4+j][n];
        *(s16x4*)&Vt[(size_t)(td + n)*SP + ts + c4] = o;
    }
}

// per-64-key-block partial sums of V, then per-head suffix sums
__global__ __launch_bounds__(64)
void sv_partial(const short* __restrict__ Vb, float* __restrict__ PB)
{
    int b = blockIdx.x, h = blockIdx.y, d = threadIdx.x;
    float s = 0.f;
#pragma unroll 8
    for (int k = 0; k < 64; ++k)
        s += bf2f(Vb[(size_t)(b*64 + k)*DM + h*HD + d]);
    PB[((size_t)h*32 + b)*64 + d] = s;
}
__global__ __launch_bounds__(64)
void sv_suffix(const float* __restrict__ PB, float* __restrict__ SSV)
{
    int h = blockIdx.x, d = threadIdx.x;
    float s = 0.f;
    SSV[((size_t)h*33 + 32)*64 + d] = 0.f;
    for (int b = 31; b >= 0; --b){
        s += PB[((size_t)h*32 + b)*64 + d];
        SSV[((size_t)h*33 + b)*64 + d] = s;
    }
}

// ---------------- Flash attention: 2-wave split-K, de-strided layouts -------
__global__ __launch_bounds__(128)
void attn_fwd(const short* __restrict__ QHh, const short* __restrict__ QHl,
              const short* __restrict__ KH, const short* __restrict__ Vt,
              const float* __restrict__ SSV, short* __restrict__ O)
{
    __shared__ __align__(16) short Ps[2][16*72];
    __shared__ float mrg[64][24];

    const int id = blockIdx.x;                     // 0..2047
    const int h  = (id & 7) + 8*((id >> 3) & 1);   // heads pinned per XCD
    const int qt = 127 - (id >> 4);                // descending diag = LPT
    const int diag = qt >> 2;

    const int tid = threadIdx.x, lane = tid & 63, wid = tid >> 6;  // wid 0..1
    const int lr = lane & 15, lg = lane >> 4;
    const int qrow = qt*16 + lg*4;

    // Q fragments, head-major rows (128B stride)
    const short* qbh = QHh + ((size_t)h*S_LEN + qt*16)*HD;
    const short* qbl = QHl + ((size_t)h*S_LEN + qt*16)*HD;
    s16x8 aqh[2], aql[2];
#pragma unroll
    for (int kc = 0; kc < 2; ++kc){
        aqh[kc] = *(const s16x8*)&qbh[lr*HD + kc*32 + lg*8];
        aql[kc] = *(const s16x8*)&qbl[lr*HD + kc*32 + lg*8];
    }

    float m_run[4], l_run[4];
    f32x4 acc_o[4];
#pragma unroll
    for (int v = 0; v < 4; ++v){ m_run[v] = -1e30f; l_run[v] = 0.f; }
#pragma unroll
    for (int n = 0; n < 4; ++n) acc_o[n] = (f32x4){0.f,0.f,0.f,0.f};

    const short* kb0 = KH + (size_t)h*S_LEN*HD;
    const short* vb0 = Vt + (size_t)(h*HD)*SP;

    // prologue: this wave's first K block
    s16x8 bkc[2][4];
    if (wid <= diag){
        const short* kb = kb0 + (size_t)(wid*64)*HD;
#pragma unroll
        for (int kc = 0; kc < 2; ++kc)
#pragma unroll
            for (int n = 0; n < 4; ++n)
                bkc[kc][n] = *(const s16x8*)&kb[(n*16 + lr)*HD + kc*32 + lg*8];
    }

    for (int kvb = wid; kvb <= diag; kvb += 2){
        // prefetch next K (stride 2)
        s16x8 bkn[2][4];
        if (kvb + 2 <= diag){
            const short* kb = kb0 + (size_t)((kvb+2)*64)*HD;
#pragma unroll
            for (int kc = 0; kc < 2; ++kc)
#pragma unroll
                for (int n = 0; n < 4; ++n)
                    bkn[kc][n] = *(const s16x8*)&kb[(n*16 + lr)*HD + kc*32 + lg*8];
        }

        f32x4 sc[4];
#pragma unroll
        for (int n = 0; n < 4; ++n) sc[n] = (f32x4){0.f,0.f,0.f,0.f};
#pragma unroll
        for (int kc = 0; kc < 2; ++kc)
#pragma unroll
            for (int n = 0; n < 4; ++n){
                sc[n] = MFMA16(aqh[kc], bkc[kc][n], sc[n]);
                sc[n] = MFMA16(aql[kc], bkc[kc][n], sc[n]);
            }

        // V fragment loads (padded stride); hidden under softmax
        const short* vb = vb0 + kvb*64;
        s16x8 bv0[4], bv1[4];
#pragma unroll
        for (int n = 0; n < 4; ++n){
            bv0[n] = *(const s16x8*)&vb[(size_t)(16*n + lr)*SP + lg*8];
            bv1[n] = *(const s16x8*)&vb[(size_t)(16*n + lr)*SP + 32 + lg*8];
        }

        // soft-threshold (+ causal mask only in the diagonal block)
        float p[4][4], tmax[4];
#pragma unroll
        for (int v = 0; v < 4; ++v) tmax[v] = -1e30f;
        if (kvb == diag){
#pragma unroll
            for (int n = 0; n < 4; ++n){
                int key = kvb*64 + n*16 + lr;
#pragma unroll
                for (int v = 0; v < 4; ++v){
                    float w;
                    if (key > qrow + v) w = CMASK;
                    else {
                        float sv = sc[n][v];
                        float sig = 1.f / (1.f + __expf(-SLOPE*sv));
                        w = CMASK + (sv - CMASK)*sig;
                    }
                    p[n][v] = w;
                    tmax[v] = fmaxf(tmax[v], w);
                }
            }
        } else {
#pragma unroll
            for (int n = 0; n < 4; ++n)
#pragma unroll
                for (int v = 0; v < 4; ++v){
                    float sv = sc[n][v];
                    float sig = 1.f / (1.f + __expf(-SLOPE*sv));
                    float w = CMASK + (sv - CMASK)*sig;
                    p[n][v] = w;
                    tmax[v] = fmaxf(tmax[v], w);
                }
        }
#pragma unroll
        for (int v = 0; v < 4; ++v)
#pragma unroll
            for (int msk = 1; msk < 16; msk <<= 1)
                tmax[v] = fmaxf(tmax[v], __shfl_xor(tmax[v], msk, 64));

        float scale[4], rsum[4];
#pragma unroll
        for (int v = 0; v < 4; ++v){
            float mn = fmaxf(m_run[v], tmax[v]);
            scale[v] = __expf(m_run[v] - mn);
            m_run[v] = mn;
            rsum[v] = 0.f;
        }
#pragma unroll
        for (int n = 0; n < 4; ++n)
#pragma unroll
            for (int v = 0; v < 4; ++v){
                float e = __expf(p[n][v] - m_run[v]);
                p[n][v] = e;
                rsum[v] += e;
            }
#pragma unroll
        for (int v = 0; v < 4; ++v){
#pragma unroll
            for (int msk = 1; msk < 16; msk <<= 1)
                rsum[v] += __shfl_xor(rsum[v], msk, 64);
            l_run[v] = l_run[v]*scale[v] + rsum[v];
        }
#pragma unroll
        for (int n = 0; n < 4; ++n)
#pragma unroll
            for (int v = 0; v < 4; ++v) acc_o[n][v] *= scale[v];

        // P (D-layout) -> per-wave LDS -> A-frag layout
#pragma unroll
        for (int n = 0; n < 4; ++n)
#pragma unroll
            for (int v = 0; v < 4; ++v)
                Ps[wid][(lg*4 + v)*72 + 16*n + lr] = f2bf(p[n][v]);
        asm volatile("s_waitcnt lgkmcnt(0)" ::: "memory");

        s16x8 pa0 = *(const s16x8*)&Ps[wid][lr*72 + lg*8];
        s16x8 pa1 = *(const s16x8*)&Ps[wid][lr*72 + 32 + lg*8];
#pragma unroll
        for (int n = 0; n < 4; ++n){
            acc_o[n] = MFMA16(pa0, bv0[n], acc_o[n]);
            acc_o[n] = MFMA16(pa1, bv1[n], acc_o[n]);
        }

        // rotate prefetched K
#pragma unroll
        for (int kc = 0; kc < 2; ++kc)
#pragma unroll
            for (int n = 0; n < 4; ++n) bkc[kc][n] = bkn[kc][n];
    }

    // ---- split-K merge: wave1 publishes, wave0 merges ----
    if (wid == 1){
#pragma unroll
        for (int v = 0; v < 4; ++v){
            mrg[lane][v] = m_run[v];
            mrg[lane][4 + v] = l_run[v];
        }
#pragma unroll
        for (int n = 0; n < 4; ++n)
#pragma unroll
            for (int v = 0; v < 4; ++v) mrg[lane][8 + n*4 + v] = acc_o[n][v];
    }
    __syncthreads();
    if (wid != 0) return;

    {
        float e0[4], e1[4];
#pragma unroll
        for (int v = 0; v < 4; ++v){
            float m1 = mrg[lane][v], l1 = mrg[lane][4 + v];
            float mn = fmaxf(m_run[v], m1);
            e0[v] = __expf(m_run[v] - mn);   // empty wave: 0
            e1[v] = __expf(m1 - mn);
            l_run[v] = l_run[v]*e0[v] + l1*e1[v];
            m_run[v] = mn;
        }
#pragma unroll
        for (int n = 0; n < 4; ++n)
#pragma unroll
            for (int v = 0; v < 4; ++v)
                acc_o[n][v] = acc_o[n][v]*e0[v] + mrg[lane][8 + n*4 + v]*e1[v];
    }

    // analytic masked-future tail
    {
        const float* sv = SSV + ((size_t)h*33 + (diag + 1))*64;
        float F = (float)(S_LEN - 64*(diag + 1));
        float e[4];
#pragma unroll
        for (int v = 0; v < 4; ++v){
            e[v] = __expf(CMASK - m_run[v]);
            l_run[v] += e[v]*F;
        }
#pragma unroll
        for (int n = 0; n < 4; ++n){
            float svv = sv[16*n + lr];
#pragma unroll
            for (int v = 0; v < 4; ++v) acc_o[n][v] += e[v]*svv;
        }
    }

    // normalize + bf16 store ([s][1024] for GEMM2)
#pragma unroll
    for (int n = 0; n < 4; ++n)
#pragma unroll
        for (int v = 0; v < 4; ++v){
            int row = qt*16 + lg*4 + v;
            int col = h*HD + 16*n + lr;
            O[(size_t)row*DM + col] = f2bf(acc_o[n][v] / l_run[v]);
        }
}

extern "C" void kernel_launch(void* const* d_in, const int* in_sizes, int n_in,
                              void* d_out, int out_size, void* d_ws, size_t ws_size,
                              hipStream_t stream)
{
    (void)in_sizes; (void)n_in; (void)out_size; (void)ws_size;
    const float* hs   = (const float*)d_in[0];
    const float* wqkv = (const float*)d_in[1];
    const float* bqkv = (const float*)d_in[2];
    const float* wprj = (const float*)d_in[3];
    const float* bprj = (const float*)d_in[4];

    char* p = (char*)d_ws;                       // ~43 MiB used
    short* Ahg  = (short*)(p + (0ull  << 20));   // 4 MiB  (later: O)
    short* Alg  = (short*)(p + (4ull  << 20));   // 4 MiB
    short* WqTh = (short*)(p + (8ull  << 20));   // 6 MiB  (later: WpT)
    short* WqTl = (short*)(p + (14ull << 20));   // 6 MiB
    short* QHh  = (short*)(p + (20ull << 20));   // 4 MiB (head-major)
    short* QHl  = (short*)(p + (24ull << 20));
    short* KH   = (short*)(p + (28ull << 20));   // 4 MiB (head-major)
    short* Vbg  = (short*)(p + (32ull << 20));   // 4 MiB ([s][1024])
    short* VT   = (short*)(p + (36ull << 20));   // 4.1 MiB ([1024][2080])
    float* PB   = (float*)(p + (41ull << 20));   // 128 KiB
    float* SSV  = (float*)(p + (42ull << 20));   // 132 KiB
    short* O    = Ahg;                           // reuse after GEMM1
    short* WpT  = WqTh;                          // reuse after GEMM1

    split_f32<<<S_LEN*DM/4/256, 256, 0, stream>>>(hs, Ahg, Alg, S_LEN*DM/4);
    wtrans<true><<<dim3(3*DM/64, DM/64), 256, 0, stream>>>(wqkv, 3*DM, WqTh, WqTl);

    // Q: split x split; K,V: plain bf16
    gemm_s<true, 0><<<dim3(8, 16), 256, 0, stream>>>(
        Ahg, Alg, WqTh, WqTl, bqkv, QHh, QHl, nullptr);
    gemm_s<false, 1><<<dim3(8, 16), 256, 0, stream>>>(
        Ahg, nullptr, WqTh + (size_t)DM*DM, nullptr, bqkv + DM, KH, nullptr, nullptr);
    gemm_s<false, 2><<<dim3(8, 16), 256, 0, stream>>>(
        Ahg, nullptr, WqTh + (size_t)2*DM*DM, nullptr, bqkv + 2*DM, Vbg, nullptr, nullptr);

    wtrans<false><<<dim3(DM/64, DM/64), 256, 0, stream>>>(wprj, DM, WpT, nullptr);
    vtrans<<<dim3(DM/64, S_LEN/64), 256, 0, stream>>>(Vbg, VT);
    sv_partial<<<dim3(32, NH), 64, 0, stream>>>(Vbg, PB);
    sv_suffix<<<NH, 64, 0, stream>>>(PB, SSV);

    attn_fwd<<<2048, 128, 0, stream>>>(QHh, QHl, KH, VT, SSV, O);

    gemm_s<false, 3><<<dim3(8, 16), 256, 0, stream>>>(
        O, nullptr, WpT, nullptr, bprj, nullptr, nullptr, (float*)d_out);
}

// Round 12
// 182.061 us; speedup vs baseline: 1.0196x; 1.0196x over previous
//
#include <hip/hip_runtime.h>

// GPT2 attention w/ soft-threshold pruning — round 12.
// r11 + workspace-layout fix: VT [1024][2080] ends at 36.06 MiB, but PB/SSV/ML
// were placed at 35.5-36.5 MiB INSIDE it -> sv_* corrupted V^T, attn_chunk's
// ML writes raced its VT reads, bf16-inf partials x zero merge weights = NaN.
// PB/SSV/ML moved past 38 MiB. No algorithmic change vs r11.

#define S_LEN 2048
#define DM    1024
#define NH    16
#define HD    64
#define SLOPE 10.0f
#define CMASK -10000.0f
#define SP    2080      // padded V^T row stride (shorts)

typedef short s16x4 __attribute__((ext_vector_type(4)));
typedef short s16x8 __attribute__((ext_vector_type(8)));
typedef float f32x4 __attribute__((ext_vector_type(4)));

#define MFMA16(a,b,c) __builtin_amdgcn_mfma_f32_16x16x32_bf16(a,b,c,0,0,0)
#define GLDS16(g,l) __builtin_amdgcn_global_load_lds( \
    (const __attribute__((address_space(1))) void*)(g), \
    (__attribute__((address_space(3))) void*)(l), 16, 0, 0)

__device__ __forceinline__ short f2bf(float f){
    unsigned u = __float_as_uint(f);
    u += 0x7fffu + ((u >> 16) & 1u);          // RNE
    return (short)(u >> 16);
}
__device__ __forceinline__ float bf2f(short x){
    return __uint_as_float(((unsigned)(unsigned short)x) << 16);
}
struct bfpair { short hi, lo; };
__device__ __forceinline__ bfpair split_bf(float x){
    bfpair r; r.hi = f2bf(x);
    r.lo = f2bf(x - bf2f(r.hi));
    return r;
}

// ---- GEMM staging: [ROWS][64] bf16 tile via global_load_lds, XOR-swizzled ----
template<int ROWS, int THREADS>
__device__ __forceinline__ void stage_tile(const short* gbase, int rstride,
                                           short* lds, int tid){
#pragma unroll
    for (int it = 0; it < ROWS*8/THREADS; ++it){
        int s = it*THREADS + tid;
        int row = s >> 3, grp = s & 7;
        const short* src = gbase + (size_t)row*rstride + ((grp ^ (row & 7)) << 3);
        GLDS16(src, lds + (size_t)s*8);
    }
}
__device__ __forceinline__ s16x8 frag(const short* lds, int row, int kg){
    return *(const s16x8*)&lds[row*64 + ((kg ^ (row & 7)) << 3)];
}

// ---------- QKV GEMM, single dispatch: grid (24,16), 128x128 tiles ----------
// sec = bcol>>10: 0 = Q (split x split, 3 MFMA, split head-major out),
// 1 = K (plain, bf16 head-major out), 2 = V (plain, bf16 [s][1024] out).
__global__ __launch_bounds__(256)
void gemm_qkv(const short* __restrict__ Ahg, const short* __restrict__ Alg,
              const short* __restrict__ Bhg, const short* __restrict__ Blg,
              const float* __restrict__ bias,
              short* __restrict__ QHh, short* __restrict__ QHl,
              short* __restrict__ KH,  short* __restrict__ Vb)
{
    __shared__ __align__(16) short Ah_s[128*64];
    __shared__ __align__(16) short Bh_s[128*64];
    __shared__ __align__(16) short Al_s[128*64];
    __shared__ __align__(16) short Bl_s[128*64];

    const int tid = threadIdx.x, lane = tid & 63, wid = tid >> 6;
    const int lr = lane & 15, lg = lane >> 4;
    const int brow = blockIdx.y*128, bcol = blockIdx.x*128;
    const int sec = bcol >> 10;
    const int wm = (wid >> 1)*64, wn = (wid & 1)*64;

    f32x4 acc[4][4];
#pragma unroll
    for (int m = 0; m < 4; ++m)
#pragma unroll
        for (int n = 0; n < 4; ++n) acc[m][n] = (f32x4){0.f,0.f,0.f,0.f};

    for (int k0 = 0; k0 < DM; k0 += 64){
        stage_tile<128,256>(Ahg + (size_t)brow*DM + k0, DM, Ah_s, tid);
        stage_tile<128,256>(Bhg + (size_t)bcol*DM + k0, DM, Bh_s, tid);
        if (sec == 0){
            stage_tile<128,256>(Alg + (size_t)brow*DM + k0, DM, Al_s, tid);
            stage_tile<128,256>(Blg + (size_t)bcol*DM + k0, DM, Bl_s, tid);
        }
        __syncthreads();
#pragma unroll
        for (int kc = 0; kc < 2; ++kc){
            s16x8 ah[4], al[4], bh[4], bl[4];
#pragma unroll
            for (int m = 0; m < 4; ++m)
                ah[m] = frag(Ah_s, wm + m*16 + lr, kc*4 + lg);
#pragma unroll
            for (int n = 0; n < 4; ++n)
                bh[n] = frag(Bh_s, wn + n*16 + lr, kc*4 + lg);
            if (sec == 0){
#pragma unroll
                for (int m = 0; m < 4; ++m)
                    al[m] = frag(Al_s, wm + m*16 + lr, kc*4 + lg);
#pragma unroll
                for (int n = 0; n < 4; ++n)
                    bl[n] = frag(Bl_s, wn + n*16 + lr, kc*4 + lg);
            }
#pragma unroll
            for (int m = 0; m < 4; ++m)
#pragma unroll
                for (int n = 0; n < 4; ++n){
                    acc[m][n] = MFMA16(ah[m], bh[n], acc[m][n]);
                    if (sec == 0){
                        acc[m][n] = MFMA16(ah[m], bl[n], acc[m][n]);
                        acc[m][n] = MFMA16(al[m], bh[n], acc[m][n]);
                    }
                }
        }
        __syncthreads();
    }

#pragma unroll
    for (int m = 0; m < 4; ++m)
#pragma unroll
        for (int n = 0; n < 4; ++n){
            int row  = brow + wm + m*16 + lg*4;
            int gcol = bcol + wn + n*16 + lr;
            float bv = bias[gcol];
            int h0 = (gcol & 1023) >> 6, d = gcol & 63;
#pragma unroll
            for (int v = 0; v < 4; ++v){
                float val = acc[m][n][v] + bv;
                if (sec == 0){
                    bfpair p = split_bf(val);
                    size_t o = ((size_t)h0*S_LEN + row + v)*HD + d;
                    QHh[o] = p.hi; QHl[o] = p.lo;
                } else if (sec == 1){
                    KH[((size_t)h0*S_LEN + row + v)*HD + d] = f2bf(val);
                } else {
                    Vb[(size_t)(row + v)*DM + (gcol & 1023)] = f2bf(val);
                }
            }
        }
}

// ---------------- proj GEMM: C = A@W^T + bias, f32 out ----------------
__global__ __launch_bounds__(256)
void gemm_proj(const short* __restrict__ Ahg, const short* __restrict__ Bhg,
               const float* __restrict__ bias, float* __restrict__ C)
{
    __shared__ __align__(16) short Ah_s[128*64];
    __shared__ __align__(16) short Bh_s[128*64];

    const int tid = threadIdx.x, lane = tid & 63, wid = tid >> 6;
    const int lr = lane & 15, lg = lane >> 4;
    const int brow = blockIdx.y*128, bcol = blockIdx.x*128;
    const int wm = (wid >> 1)*64, wn = (wid & 1)*64;

    f32x4 acc[4][4];
#pragma unroll
    for (int m = 0; m < 4; ++m)
#pragma unroll
        for (int n = 0; n < 4; ++n) acc[m][n] = (f32x4){0.f,0.f,0.f,0.f};

    for (int k0 = 0; k0 < DM; k0 += 64){
        stage_tile<128,256>(Ahg + (size_t)brow*DM + k0, DM, Ah_s, tid);
        stage_tile<128,256>(Bhg + (size_t)bcol*DM + k0, DM, Bh_s, tid);
        __syncthreads();
#pragma unroll
        for (int kc = 0; kc < 2; ++kc){
            s16x8 ah[4], bh[4];
#pragma unroll
            for (int m = 0; m < 4; ++m)
                ah[m] = frag(Ah_s, wm + m*16 + lr, kc*4 + lg);
#pragma unroll
            for (int n = 0; n < 4; ++n)
                bh[n] = frag(Bh_s, wn + n*16 + lr, kc*4 + lg);
#pragma unroll
            for (int m = 0; m < 4; ++m)
#pragma unroll
                for (int n = 0; n < 4; ++n)
                    acc[m][n] = MFMA16(ah[m], bh[n], acc[m][n]);
        }
        __syncthreads();
    }

#pragma unroll
    for (int m = 0; m < 4; ++m)
#pragma unroll
        for (int n = 0; n < 4; ++n){
            int row  = brow + wm + m*16 + lg*4;
            int gcol = bcol + wn + n*16 + lr;
            float bv = bias[gcol];
#pragma unroll
            for (int v = 0; v < 4; ++v)
                C[(size_t)(row + v)*DM + gcol] = acc[m][n][v] + bv;
        }
}

// ---------------- prep kernels ----------------
__global__ __launch_bounds__(256)
void split_f32(const float* __restrict__ x, short* __restrict__ h,
               short* __restrict__ l, int n4)
{
    int i = blockIdx.x*256 + threadIdx.x;
    if (i >= n4) return;
    float4 v = *(const float4*)&x[(size_t)i*4];
    bfpair a = split_bf(v.x), b = split_bf(v.y), c = split_bf(v.z), d = split_bf(v.w);
    s16x4 hv, lv;
    hv.x = a.hi; hv.y = b.hi; hv.z = c.hi; hv.w = d.hi;
    lv.x = a.lo; lv.y = b.lo; lv.z = c.lo; lv.w = d.lo;
    *(s16x4*)&h[(size_t)i*4] = hv;
    *(s16x4*)&l[(size_t)i*4] = lv;
}

// W [1024][N] f32 -> W^T [N][1024] bf16 hi; lo only for first 1024 cols if SPL
template<bool SPL>
__global__ __launch_bounds__(256)
void wtrans(const float* __restrict__ W, int N, short* __restrict__ Th,
            short* __restrict__ Tl)
{
    __shared__ float t[64][65];
    const int tid = threadIdx.x;
    const int tn = blockIdx.x*64, tk = blockIdx.y*64;
#pragma unroll
    for (int it = 0; it < 4; ++it){
        int idx = tid + it*256;
        int r = idx >> 4, c4 = (idx & 15)*4;
        float4 v = *(const float4*)&W[(size_t)(tk + r)*N + tn + c4];
        t[r][c4] = v.x; t[r][c4+1] = v.y; t[r][c4+2] = v.z; t[r][c4+3] = v.w;
    }
    __syncthreads();
#pragma unroll
    for (int it = 0; it < 4; ++it){
        int idx = tid + it*256;
        int n = idx >> 4, c4 = (idx & 15)*4;
        s16x4 hv, lv;
#pragma unroll
        for (int j = 0; j < 4; ++j){
            bfpair p = split_bf(t[c4+j][n]);
            hv[j] = p.hi; lv[j] = p.lo;
        }
        *(s16x4*)&Th[(size_t)(tn + n)*DM + tk + c4] = hv;
        if (SPL && tn < DM)
            *(s16x4*)&Tl[(size_t)(tn + n)*DM + tk + c4] = lv;
    }
}

// V [2048][1024] bf16 -> V^T [1024][SP] bf16 (padded stride)
__global__ __launch_bounds__(256)
void vtrans(const short* __restrict__ Vb, short* __restrict__ Vt)
{
    __shared__ short t[64][66];
    const int tid = threadIdx.x;
    const int td = blockIdx.x*64, ts = blockIdx.y*64;
#pragma unroll
    for (int it = 0; it < 4; ++it){
        int idx = tid + it*256;
        int r = idx >> 4, c4 = (idx & 15)*4;
        s16x4 v = *(const s16x4*)&Vb[(size_t)(ts + r)*DM + td + c4];
        t[r][c4] = v.x; t[r][c4+1] = v.y; t[r][c4+2] = v.z; t[r][c4+3] = v.w;
    }
    __syncthreads();
#pragma unroll
    for (int it = 0; it < 4; ++it){
        int idx = tid + it*256;
        int n = idx >> 4, c4 = (idx & 15)*4;
        s16x4 o;
#pragma unroll
        for (int j = 0; j < 4; ++j) o[j] = t[c4+j][n];
        *(s16x4*)&Vt[(size_t)(td + n)*SP + ts + c4] = o;
    }
}

// per-64-key-block partial sums of V, then per-head suffix sums
__global__ __launch_bounds__(64)
void sv_partial(const short* __restrict__ Vb, float* __restrict__ PB)
{
    int b = blockIdx.x, h = blockIdx.y, d = threadIdx.x;
    float s = 0.f;
#pragma unroll 8
    for (int k = 0; k < 64; ++k)
        s += bf2f(Vb[(size_t)(b*64 + k)*DM + h*HD + d]);
    PB[((size_t)h*32 + b)*64 + d] = s;
}
__global__ __launch_bounds__(64)
void sv_suffix(const float* __restrict__ PB, float* __restrict__ SSV)
{
    int h = blockIdx.x, d = threadIdx.x;
    float s = 0.f;
    SSV[((size_t)h*33 + 32)*64 + d] = 0.f;
    for (int b = 31; b >= 0; --b){
        s += PB[((size_t)h*32 + b)*64 + d];
        SSV[((size_t)h*33 + b)*64 + d] = s;
    }
}

// ---------------- attn, flash-decoding split-K: 5120 uniform 1-wave jobs ----
// job j: h = j&15, t = j>>4 in 0..319.
// t -> (qt, chunk): group g = qt>>5 has g+1 chunks/qt; offset(32g) = 16g(g+1).
__global__ __launch_bounds__(64)
void attn_chunk(const short* __restrict__ QHh, const short* __restrict__ QHl,
                const short* __restrict__ KH, const short* __restrict__ Vt,
                short* __restrict__ acc0, short* __restrict__ acc1,
                short* __restrict__ acc2, float* __restrict__ ML)
{
    __shared__ __align__(16) short Ps[16*72];

    const int j = blockIdx.x;
    const int h = (j & 7) + 8*((j >> 3) & 1);
    const int t = j >> 4;
    const int g = (t < 32) ? 0 : (t < 96) ? 1 : (t < 192) ? 2 : 3;
    const int u = t - 16*g*(g+1);
    const int qd = u / (g+1);
    const int qt = 32*g + qd;
    const int chunk = u - qd*(g+1);
    const int diag = qt >> 2;
    const int kv0 = chunk*8;
    const int kv1 = min(kv0 + 8, diag + 1);

    const int lane = threadIdx.x, lr = lane & 15, lg = lane >> 4;
    const int qrow = qt*16 + lg*4;

    const short* qbh = QHh + ((size_t)h*S_LEN + qt*16)*HD;
    const short* qbl = QHl + ((size_t)h*S_LEN + qt*16)*HD;
    s16x8 aqh[2], aql[2];
#pragma unroll
    for (int kc = 0; kc < 2; ++kc){
        aqh[kc] = *(const s16x8*)&qbh[lr*HD + kc*32 + lg*8];
        aql[kc] = *(const s16x8*)&qbl[lr*HD + kc*32 + lg*8];
    }

    float m_run[4], l_run[4];
    f32x4 acc_o[4];
#pragma unroll
    for (int v = 0; v < 4; ++v){ m_run[v] = -1e30f; l_run[v] = 0.f; }
#pragma unroll
    for (int n = 0; n < 4; ++n) acc_o[n] = (f32x4){0.f,0.f,0.f,0.f};

    const short* kb0 = KH + (size_t)h*S_LEN*HD;
    const short* vb0 = Vt + (size_t)(h*HD)*SP;

    for (int kvb = kv0; kvb < kv1; ++kvb){
        const short* kb = kb0 + (size_t)(kvb*64)*HD;
        s16x8 bk[2][4];
#pragma unroll
        for (int kc = 0; kc < 2; ++kc)
#pragma unroll
            for (int n = 0; n < 4; ++n)
                bk[kc][n] = *(const s16x8*)&kb[(n*16 + lr)*HD + kc*32 + lg*8];

        f32x4 sc[4];
#pragma unroll
        for (int n = 0; n < 4; ++n) sc[n] = (f32x4){0.f,0.f,0.f,0.f};
#pragma unroll
        for (int kc = 0; kc < 2; ++kc)
#pragma unroll
            for (int n = 0; n < 4; ++n){
                sc[n] = MFMA16(aqh[kc], bk[kc][n], sc[n]);
                sc[n] = MFMA16(aql[kc], bk[kc][n], sc[n]);
            }

        // V fragment loads (padded stride); latency hides under softmax
        const short* vb = vb0 + kvb*64;
        s16x8 bv0[4], bv1[4];
#pragma unroll
        for (int n = 0; n < 4; ++n){
            bv0[n] = *(const s16x8*)&vb[(size_t)(16*n + lr)*SP + lg*8];
            bv1[n] = *(const s16x8*)&vb[(size_t)(16*n + lr)*SP + 32 + lg*8];
        }

        float p[4][4], tmax[4];
#pragma unroll
        for (int v = 0; v < 4; ++v) tmax[v] = -1e30f;
        if (kvb == diag){
#pragma unroll
            for (int n = 0; n < 4; ++n){
                int key = kvb*64 + n*16 + lr;
#pragma unroll
                for (int v = 0; v < 4; ++v){
                    float w;
                    if (key > qrow + v) w = CMASK;
                    else {
                        float sv = sc[n][v];
                        float sig = 1.f / (1.f + __expf(-SLOPE*sv));
                        w = CMASK + (sv - CMASK)*sig;
                    }
                    p[n][v] = w;
                    tmax[v] = fmaxf(tmax[v], w);
                }
            }
        } else {
#pragma unroll
            for (int n = 0; n < 4; ++n)
#pragma unroll
                for (int v = 0; v < 4; ++v){
                    float sv = sc[n][v];
                    float sig = 1.f / (1.f + __expf(-SLOPE*sv));
                    float w = CMASK + (sv - CMASK)*sig;
                    p[n][v] = w;
                    tmax[v] = fmaxf(tmax[v], w);
                }
        }
#pragma unroll
        for (int v = 0; v < 4; ++v)
#pragma unroll
            for (int msk = 1; msk < 16; msk <<= 1)
                tmax[v] = fmaxf(tmax[v], __shfl_xor(tmax[v], msk, 64));

        float scale[4], rsum[4];
#pragma unroll
        for (int v = 0; v < 4; ++v){
            float mn = fmaxf(m_run[v], tmax[v]);
            scale[v] = __expf(m_run[v] - mn);
            m_run[v] = mn;
            rsum[v] = 0.f;
        }
#pragma unroll
        for (int n = 0; n < 4; ++n)
#pragma unroll
            for (int v = 0; v < 4; ++v){
                float e = __expf(p[n][v] - m_run[v]);
                p[n][v] = e;
                rsum[v] += e;
            }
#pragma unroll
        for (int v = 0; v < 4; ++v){
#pragma unroll
            for (int msk = 1; msk < 16; msk <<= 1)
                rsum[v] += __shfl_xor(rsum[v], msk, 64);
            l_run[v] = l_run[v]*scale[v] + rsum[v];
        }
#pragma unroll
        for (int n = 0; n < 4; ++n)
#pragma unroll
            for (int v = 0; v < 4; ++v) acc_o[n][v] *= scale[v];

        // P (D-layout) -> LDS -> A-frag layout
#pragma unroll
        for (int n = 0; n < 4; ++n)
#pragma unroll
            for (int v = 0; v < 4; ++v)
                Ps[(lg*4 + v)*72 + 16*n + lr] = f2bf(p[n][v]);
        asm volatile("s_waitcnt lgkmcnt(0)" ::: "memory");

        s16x8 pa0 = *(const s16x8*)&Ps[lr*72 + lg*8];
        s16x8 pa1 = *(const s16x8*)&Ps[lr*72 + 32 + lg*8];
#pragma unroll
        for (int n = 0; n < 4; ++n){
            acc_o[n] = MFMA16(pa0, bv0[n], acc_o[n]);
            acc_o[n] = MFMA16(pa1, bv1[n], acc_o[n]);
        }
    }

    // store partial: acc bf16 [16 rows][64], m/l f32
    short* ab = (j < 2048) ? acc0 + (size_t)j*1024
              : (j < 3072) ? acc1 + (size_t)(j-2048)*1024
                           : acc2 + (size_t)(j-3072)*1024;
#pragma unroll
    for (int n = 0; n < 4; ++n)
#pragma unroll
        for (int v = 0; v < 4; ++v)
            ab[(lg*4 + v)*64 + 16*n + lr] = f2bf(acc_o[n][v]);
    if (lr == 0){
#pragma unroll
        for (int v = 0; v < 4; ++v){
            ML[((size_t)j*16 + lg*4 + v)*2 + 0] = m_run[v];
            ML[((size_t)j*16 + lg*4 + v)*2 + 1] = l_run[v];
        }
    }
}

// ---------------- merge partials + analytic tail -> O bf16 [s][1024] --------
__global__ __launch_bounds__(64)
void attn_merge(const short* __restrict__ acc0, const short* __restrict__ acc1,
                const short* __restrict__ acc2, const float* __restrict__ ML,
                const float* __restrict__ SSV, short* __restrict__ O)
{
    const int b = blockIdx.x;          // 0..2047
    const int h = b & 15, qt = b >> 4;
    const int d = threadIdx.x;
    const int g = qt >> 5, C = g + 1;
    const int tbase = (g + 1)*(qt - 16*g);
    const int diag = qt >> 2;
    const float F = (float)(S_LEN - 64*(diag + 1));
    const float svd = SSV[((size_t)h*33 + (diag + 1))*64 + d];

    for (int r = 0; r < 16; ++r){
        float M = -1e30f;
        for (int c = 0; c < C; ++c){
            int job = (tbase + c)*16 + h;
            M = fmaxf(M, ML[((size_t)job*16 + r)*2]);
        }
        float num = 0.f, den = 0.f;
        for (int c = 0; c < C; ++c){
            int job = (tbase + c)*16 + h;
            float m = ML[((size_t)job*16 + r)*2];
            float l = ML[((size_t)job*16 + r)*2 + 1];
            const short* ab = (job < 2048) ? acc0 + (size_t)job*1024
                            : (job < 3072) ? acc1 + (size_t)(job-2048)*1024
                                           : acc2 + (size_t)(job-3072)*1024;
            float e = __expf(m - M);
            num += e * bf2f(ab[r*64 + d]);
            den += e * l;
        }
        float et = __expf(CMASK - M);
        num += et * svd;
        den += et * F;
        O[(size_t)(qt*16 + r)*DM + h*64 + d] = f2bf(num/den);
    }
}

extern "C" void kernel_launch(void* const* d_in, const int* in_sizes, int n_in,
                              void* d_out, int out_size, void* d_ws, size_t ws_size,
                              hipStream_t stream)
{
    (void)in_sizes; (void)n_in; (void)out_size; (void)ws_size;
    const float* hs   = (const float*)d_in[0];
    const float* wqkv = (const float*)d_in[1];
    const float* bqkv = (const float*)d_in[2];
    const float* wprj = (const float*)d_in[3];
    const float* bprj = (const float*)d_in[4];

    char* p = (char*)d_ws;                        // ~39.7 MiB used
    short* Ahg  = (short*)(p + (0ull  << 20));    // 4 MiB  (-> O after attn)
    short* Alg  = (short*)(p + (4ull  << 20));    // 4 MiB  (-> acc seg0: jobs 0..2047)
    short* WqTh = (short*)(p + (8ull  << 20));    // 6 MiB  (-> WpT)
    short* WqTl = (short*)(p + (14ull << 20));    // 2 MiB  (-> acc seg1: jobs 2048..3071)
    short* QHh  = (short*)(p + (16ull << 20));    // 4 MiB (head-major)
    short* QHl  = (short*)(p + (20ull << 20));    // 4 MiB
    short* KH   = (short*)(p + (24ull << 20));    // 4 MiB (head-major)
    short* Vbg  = (short*)(p + (28ull << 20));    // 4 MiB (-> acc seg2: jobs 3072..5119)
    short* VT   = (short*)(p + (32ull << 20));    // 4.07 MiB, ends at ~36.06 MiB
    float* PB   = (float*)(p + (38ull << 20));                     // 128 KiB
    float* SSV  = (float*)(p + (38ull << 20) + (256ull << 10));    // 132 KiB
    float* ML   = (float*)(p + (39ull << 20));                     // 640 KiB
    short* O    = Ahg;
    short* WpT  = WqTh;

    split_f32<<<S_LEN*DM/4/256, 256, 0, stream>>>(hs, Ahg, Alg, S_LEN*DM/4);
    wtrans<true><<<dim3(3*DM/64, DM/64), 256, 0, stream>>>(wqkv, 3*DM, WqTh, WqTl);

    gemm_qkv<<<dim3(24, 16), 256, 0, stream>>>(
        Ahg, Alg, WqTh, WqTl, bqkv, QHh, QHl, KH, Vbg);

    wtrans<false><<<dim3(DM/64, DM/64), 256, 0, stream>>>(wprj, DM, WpT, nullptr);
    vtrans<<<dim3(DM/64, S_LEN/64), 256, 0, stream>>>(Vbg, VT);
    sv_partial<<<dim3(32, NH), 64, 0, stream>>>(Vbg, PB);
    sv_suffix<<<NH, 64, 0, stream>>>(PB, SSV);

    attn_chunk<<<5120, 64, 0, stream>>>(QHh, QHl, KH, VT, Alg, WqTl, Vbg, ML);
    attn_merge<<<2048, 64, 0, stream>>>(Alg, WqTl, Vbg, ML, SSV, O);

    gemm_proj<<<dim3(8, 16), 256, 0, stream>>>(O, WpT, bprj, (float*)d_out);
}

// Round 13
// 181.617 us; speedup vs baseline: 1.0221x; 1.0024x over previous
//
#include <hip/hip_runtime.h>

// GPT2 attention w/ soft-threshold pruning — round 13.
// vs r12: attn memory-pipe fix. All r6-r12 attn variants pinned at 68-86us
// because per-wave fragment loads (16KB/wave-iter, 540MB total) saturate the
// per-CU memory pipe (~36us floor). New attn: 1280 blocks x 4 waves; block =
// (head, 64-row q-supertile, <=8 kv-blocks); K/V staged ONCE into LDS per
// kv-block and consumed by 4 waves (4x less load traffic), de-strided
// head-major layouts kept, uniform chunks + partial merge kept.

#define S_LEN 2048
#define DM    1024
#define NH    16
#define HD    64
#define SLOPE 10.0f
#define CMASK -10000.0f
#define SP    2080      // padded V^T row stride (shorts)

typedef short s16x4 __attribute__((ext_vector_type(4)));
typedef short s16x8 __attribute__((ext_vector_type(8)));
typedef float f32x4 __attribute__((ext_vector_type(4)));

#define MFMA16(a,b,c) __builtin_amdgcn_mfma_f32_16x16x32_bf16(a,b,c,0,0,0)
#define GLDS16(g,l) __builtin_amdgcn_global_load_lds( \
    (const __attribute__((address_space(1))) void*)(g), \
    (__attribute__((address_space(3))) void*)(l), 16, 0, 0)

__device__ __forceinline__ short f2bf(float f){
    unsigned u = __float_as_uint(f);
    u += 0x7fffu + ((u >> 16) & 1u);          // RNE
    return (short)(u >> 16);
}
__device__ __forceinline__ float bf2f(short x){
    return __uint_as_float(((unsigned)(unsigned short)x) << 16);
}
struct bfpair { short hi, lo; };
__device__ __forceinline__ bfpair split_bf(float x){
    bfpair r; r.hi = f2bf(x);
    r.lo = f2bf(x - bf2f(r.hi));
    return r;
}

// ---- staging: [ROWS][64] bf16 tile via global_load_lds, XOR-swizzled ----
template<int ROWS, int THREADS>
__device__ __forceinline__ void stage_tile(const short* gbase, int rstride,
                                           short* lds, int tid){
#pragma unroll
    for (int it = 0; it < ROWS*8/THREADS; ++it){
        int s = it*THREADS + tid;
        int row = s >> 3, grp = s & 7;
        const short* src = gbase + (size_t)row*rstride + ((grp ^ (row & 7)) << 3);
        GLDS16(src, lds + (size_t)s*8);
    }
}
__device__ __forceinline__ s16x8 frag(const short* lds, int row, int kg){
    return *(const s16x8*)&lds[row*64 + ((kg ^ (row & 7)) << 3)];
}

// ---------- QKV GEMM, single dispatch: grid (24,16), 128x128 tiles ----------
// sec = bcol>>10: 0 = Q (split x split, 3 MFMA, split head-major out),
// 1 = K (plain, bf16 head-major out), 2 = V (plain, bf16 [s][1024] out).
__global__ __launch_bounds__(256)
void gemm_qkv(const short* __restrict__ Ahg, const short* __restrict__ Alg,
              const short* __restrict__ Bhg, const short* __restrict__ Blg,
              const float* __restrict__ bias,
              short* __restrict__ QHh, short* __restrict__ QHl,
              short* __restrict__ KH,  short* __restrict__ Vb)
{
    __shared__ __align__(16) short Ah_s[128*64];
    __shared__ __align__(16) short Bh_s[128*64];
    __shared__ __align__(16) short Al_s[128*64];
    __shared__ __align__(16) short Bl_s[128*64];

    const int tid = threadIdx.x, lane = tid & 63, wid = tid >> 6;
    const int lr = lane & 15, lg = lane >> 4;
    const int brow = blockIdx.y*128, bcol = blockIdx.x*128;
    const int sec = bcol >> 10;
    const int wm = (wid >> 1)*64, wn = (wid & 1)*64;

    f32x4 acc[4][4];
#pragma unroll
    for (int m = 0; m < 4; ++m)
#pragma unroll
        for (int n = 0; n < 4; ++n) acc[m][n] = (f32x4){0.f,0.f,0.f,0.f};

    for (int k0 = 0; k0 < DM; k0 += 64){
        stage_tile<128,256>(Ahg + (size_t)brow*DM + k0, DM, Ah_s, tid);
        stage_tile<128,256>(Bhg + (size_t)bcol*DM + k0, DM, Bh_s, tid);
        if (sec == 0){
            stage_tile<128,256>(Alg + (size_t)brow*DM + k0, DM, Al_s, tid);
            stage_tile<128,256>(Blg + (size_t)bcol*DM + k0, DM, Bl_s, tid);
        }
        __syncthreads();
#pragma unroll
        for (int kc = 0; kc < 2; ++kc){
            s16x8 ah[4], al[4], bh[4], bl[4];
#pragma unroll
            for (int m = 0; m < 4; ++m)
                ah[m] = frag(Ah_s, wm + m*16 + lr, kc*4 + lg);
#pragma unroll
            for (int n = 0; n < 4; ++n)
                bh[n] = frag(Bh_s, wn + n*16 + lr, kc*4 + lg);
            if (sec == 0){
#pragma unroll
                for (int m = 0; m < 4; ++m)
                    al[m] = frag(Al_s, wm + m*16 + lr, kc*4 + lg);
#pragma unroll
                for (int n = 0; n < 4; ++n)
                    bl[n] = frag(Bl_s, wn + n*16 + lr, kc*4 + lg);
            }
#pragma unroll
            for (int m = 0; m < 4; ++m)
#pragma unroll
                for (int n = 0; n < 4; ++n){
                    acc[m][n] = MFMA16(ah[m], bh[n], acc[m][n]);
                    if (sec == 0){
                        acc[m][n] = MFMA16(ah[m], bl[n], acc[m][n]);
                        acc[m][n] = MFMA16(al[m], bh[n], acc[m][n]);
                    }
                }
        }
        __syncthreads();
    }

#pragma unroll
    for (int m = 0; m < 4; ++m)
#pragma unroll
        for (int n = 0; n < 4; ++n){
            int row  = brow + wm + m*16 + lg*4;
            int gcol = bcol + wn + n*16 + lr;
            float bv = bias[gcol];
            int h0 = (gcol & 1023) >> 6, d = gcol & 63;
#pragma unroll
            for (int v = 0; v < 4; ++v){
                float val = acc[m][n][v] + bv;
                if (sec == 0){
                    bfpair p = split_bf(val);
                    size_t o = ((size_t)h0*S_LEN + row + v)*HD + d;
                    QHh[o] = p.hi; QHl[o] = p.lo;
                } else if (sec == 1){
                    KH[((size_t)h0*S_LEN + row + v)*HD + d] = f2bf(val);
                } else {
                    Vb[(size_t)(row + v)*DM + (gcol & 1023)] = f2bf(val);
                }
            }
        }
}

// ---------------- proj GEMM: C = A@W^T + bias, f32 out ----------------
__global__ __launch_bounds__(256)
void gemm_proj(const short* __restrict__ Ahg, const short* __restrict__ Bhg,
               const float* __restrict__ bias, float* __restrict__ C)
{
    __shared__ __align__(16) short Ah_s[128*64];
    __shared__ __align__(16) short Bh_s[128*64];

    const int tid = threadIdx.x, lane = tid & 63, wid = tid >> 6;
    const int lr = lane & 15, lg = lane >> 4;
    const int brow = blockIdx.y*128, bcol = blockIdx.x*128;
    const int wm = (wid >> 1)*64, wn = (wid & 1)*64;

    f32x4 acc[4][4];
#pragma unroll
    for (int m = 0; m < 4; ++m)
#pragma unroll
        for (int n = 0; n < 4; ++n) acc[m][n] = (f32x4){0.f,0.f,0.f,0.f};

    for (int k0 = 0; k0 < DM; k0 += 64){
        stage_tile<128,256>(Ahg + (size_t)brow*DM + k0, DM, Ah_s, tid);
        stage_tile<128,256>(Bhg + (size_t)bcol*DM + k0, DM, Bh_s, tid);
        __syncthreads();
#pragma unroll
        for (int kc = 0; kc < 2; ++kc){
            s16x8 ah[4], bh[4];
#pragma unroll
            for (int m = 0; m < 4; ++m)
                ah[m] = frag(Ah_s, wm + m*16 + lr, kc*4 + lg);
#pragma unroll
            for (int n = 0; n < 4; ++n)
                bh[n] = frag(Bh_s, wn + n*16 + lr, kc*4 + lg);
#pragma unroll
            for (int m = 0; m < 4; ++m)
#pragma unroll
                for (int n = 0; n < 4; ++n)
                    acc[m][n] = MFMA16(ah[m], bh[n], acc[m][n]);
        }
        __syncthreads();
    }

#pragma unroll
    for (int m = 0; m < 4; ++m)
#pragma unroll
        for (int n = 0; n < 4; ++n){
            int row  = brow + wm + m*16 + lg*4;
            int gcol = bcol + wn + n*16 + lr;
            float bv = bias[gcol];
#pragma unroll
            for (int v = 0; v < 4; ++v)
                C[(size_t)(row + v)*DM + gcol] = acc[m][n][v] + bv;
        }
}

// ---------------- prep kernels ----------------
__global__ __launch_bounds__(256)
void split_f32(const float* __restrict__ x, short* __restrict__ h,
               short* __restrict__ l, int n4)
{
    int i = blockIdx.x*256 + threadIdx.x;
    if (i >= n4) return;
    float4 v = *(const float4*)&x[(size_t)i*4];
    bfpair a = split_bf(v.x), b = split_bf(v.y), c = split_bf(v.z), d = split_bf(v.w);
    s16x4 hv, lv;
    hv.x = a.hi; hv.y = b.hi; hv.z = c.hi; hv.w = d.hi;
    lv.x = a.lo; lv.y = b.lo; lv.z = c.lo; lv.w = d.lo;
    *(s16x4*)&h[(size_t)i*4] = hv;
    *(s16x4*)&l[(size_t)i*4] = lv;
}

// W [1024][N] f32 -> W^T [N][1024] bf16 hi; lo only for first 1024 cols if SPL
template<bool SPL>
__global__ __launch_bounds__(256)
void wtrans(const float* __restrict__ W, int N, short* __restrict__ Th,
            short* __restrict__ Tl)
{
    __shared__ float t[64][65];
    const int tid = threadIdx.x;
    const int tn = blockIdx.x*64, tk = blockIdx.y*64;
#pragma unroll
    for (int it = 0; it < 4; ++it){
        int idx = tid + it*256;
        int r = idx >> 4, c4 = (idx & 15)*4;
        float4 v = *(const float4*)&W[(size_t)(tk + r)*N + tn + c4];
        t[r][c4] = v.x; t[r][c4+1] = v.y; t[r][c4+2] = v.z; t[r][c4+3] = v.w;
    }
    __syncthreads();
#pragma unroll
    for (int it = 0; it < 4; ++it){
        int idx = tid + it*256;
        int n = idx >> 4, c4 = (idx & 15)*4;
        s16x4 hv, lv;
#pragma unroll
        for (int j = 0; j < 4; ++j){
            bfpair p = split_bf(t[c4+j][n]);
            hv[j] = p.hi; lv[j] = p.lo;
        }
        *(s16x4*)&Th[(size_t)(tn + n)*DM + tk + c4] = hv;
        if (SPL && tn < DM)
            *(s16x4*)&Tl[(size_t)(tn + n)*DM + tk + c4] = lv;
    }
}

// V [2048][1024] bf16 -> V^T [1024][SP] bf16 (padded stride)
__global__ __launch_bounds__(256)
void vtrans(const short* __restrict__ Vb, short* __restrict__ Vt)
{
    __shared__ short t[64][66];
    const int tid = threadIdx.x;
    const int td = blockIdx.x*64, ts = blockIdx.y*64;
#pragma unroll
    for (int it = 0; it < 4; ++it){
        int idx = tid + it*256;
        int r = idx >> 4, c4 = (idx & 15)*4;
        s16x4 v = *(const s16x4*)&Vb[(size_t)(ts + r)*DM + td + c4];
        t[r][c4] = v.x; t[r][c4+1] = v.y; t[r][c4+2] = v.z; t[r][c4+3] = v.w;
    }
    __syncthreads();
#pragma unroll
    for (int it = 0; it < 4; ++it){
        int idx = tid + it*256;
        int n = idx >> 4, c4 = (idx & 15)*4;
        s16x4 o;
#pragma unroll
        for (int j = 0; j < 4; ++j) o[j] = t[c4+j][n];
        *(s16x4*)&Vt[(size_t)(td + n)*SP + ts + c4] = o;
    }
}

// per-64-key-block partial sums of V, then per-head suffix sums
__global__ __launch_bounds__(64)
void sv_partial(const short* __restrict__ Vb, float* __restrict__ PB)
{
    int b = blockIdx.x, h = blockIdx.y, d = threadIdx.x;
    float s = 0.f;
#pragma unroll 8
    for (int k = 0; k < 64; ++k)
        s += bf2f(Vb[(size_t)(b*64 + k)*DM + h*HD + d]);
    PB[((size_t)h*32 + b)*64 + d] = s;
}
__global__ __launch_bounds__(64)
void sv_suffix(const float* __restrict__ PB, float* __restrict__ SSV)
{
    int h = blockIdx.x, d = threadIdx.x;
    float s = 0.f;
    SSV[((size_t)h*33 + 32)*64 + d] = 0.f;
    for (int b = 31; b >= 0; --b){
        s += PB[((size_t)h*32 + b)*64 + d];
        SSV[((size_t)h*33 + b)*64 + d] = s;
    }
}

// -------- attn: 1280 blocks x 4 waves; block = (h, 64-row q-tile, <=8 kvb) --
// t = j>>4 in 0..79 -> (qst, chunk): qst<8:1 chunk, <16:2, <24:3, <32:4.
// K/V staged once into LDS per kv-block, consumed by 4 waves (16 rows each).
__global__ __launch_bounds__(256)
void attn_fwd(const short* __restrict__ QHh, const short* __restrict__ QHl,
              const short* __restrict__ KH, const short* __restrict__ Vt,
              short* __restrict__ acc0, short* __restrict__ acc1,
              short* __restrict__ acc2, float* __restrict__ ML)
{
    __shared__ __align__(16) short kh_s[64*64];
    __shared__ __align__(16) short vt_s[64*64];
    __shared__ __align__(16) short Ps[4][16*72];

    const int j = blockIdx.x;                      // 0..1279
    const int h = (j & 7) + 8*((j >> 3) & 1);      // == j&15; XCD-pinned heads
    const int t = j >> 4;                          // 0..79
    int qst, c;
    if (t < 8)      { qst = t; c = 0; }
    else if (t < 24){ int u = t - 8;  qst = 8  + (u >> 1); c = u & 1; }
    else if (t < 48){ int u = t - 24; qst = 16 + u/3;      c = u - (u/3)*3; }
    else            { int u = t - 48; qst = 24 + (u >> 2); c = u & 3; }
    const int kv0 = c*8;
    const int kv1 = min(kv0 + 8, qst + 1);         // diag block for all rows = qst

    const int tid = threadIdx.x, lane = tid & 63, wid = tid >> 6;
    const int lr = lane & 15, lg = lane >> 4;
    const int qrow = qst*64 + wid*16 + lg*4;

    // Q fragments direct from global (head-major, 128B rows)
    const short* qbh = QHh + ((size_t)h*S_LEN + qst*64 + wid*16)*HD;
    const short* qbl = QHl + ((size_t)h*S_LEN + qst*64 + wid*16)*HD;
    s16x8 aqh[2], aql[2];
#pragma unroll
    for (int kc = 0; kc < 2; ++kc){
        aqh[kc] = *(const s16x8*)&qbh[lr*HD + kc*32 + lg*8];
        aql[kc] = *(const s16x8*)&qbl[lr*HD + kc*32 + lg*8];
    }

    float m_run[4], l_run[4];
    f32x4 acc_o[4];
#pragma unroll
    for (int v = 0; v < 4; ++v){ m_run[v] = -1e30f; l_run[v] = 0.f; }
#pragma unroll
    for (int n = 0; n < 4; ++n) acc_o[n] = (f32x4){0.f,0.f,0.f,0.f};

    for (int kvb = kv0; kvb < kv1; ++kvb){
        __syncthreads();    // previous iter's LDS reads complete
        stage_tile<64,256>(KH + ((size_t)h*S_LEN + kvb*64)*HD, HD, kh_s, tid);
        stage_tile<64,256>(Vt + (size_t)(h*HD)*SP + kvb*64, SP, vt_s, tid);
        __syncthreads();

        // S = Q K^T (Q split hi/lo, K plain): 2 MFMA per fragment
        f32x4 sc[4];
#pragma unroll
        for (int n = 0; n < 4; ++n) sc[n] = (f32x4){0.f,0.f,0.f,0.f};
#pragma unroll
        for (int kc = 0; kc < 2; ++kc)
#pragma unroll
            for (int n = 0; n < 4; ++n){
                s16x8 bkh = frag(kh_s, n*16 + lr, kc*4 + lg);
                sc[n] = MFMA16(aqh[kc], bkh, sc[n]);
                sc[n] = MFMA16(aql[kc], bkh, sc[n]);
            }

        // soft-threshold (+ causal mask only in diagonal block kvb==qst)
        float p[4][4], tmax[4];
#pragma unroll
        for (int v = 0; v < 4; ++v) tmax[v] = -1e30f;
        if (kvb == qst){
#pragma unroll
            for (int n = 0; n < 4; ++n){
                int key = kvb*64 + n*16 + lr;
#pragma unroll
                for (int v = 0; v < 4; ++v){
                    float w;
                    if (key > qrow + v) w = CMASK;
                    else {
                        float sv = sc[n][v];
                        float sig = 1.f / (1.f + __expf(-SLOPE*sv));
                        w = CMASK + (sv - CMASK)*sig;
                    }
                    p[n][v] = w;
                    tmax[v] = fmaxf(tmax[v], w);
                }
            }
        } else {
#pragma unroll
            for (int n = 0; n < 4; ++n)
#pragma unroll
                for (int v = 0; v < 4; ++v){
                    float sv = sc[n][v];
                    float sig = 1.f / (1.f + __expf(-SLOPE*sv));
                    float w = CMASK + (sv - CMASK)*sig;
                    p[n][v] = w;
                    tmax[v] = fmaxf(tmax[v], w);
                }
        }
#pragma unroll
        for (int v = 0; v < 4; ++v)
#pragma unroll
            for (int msk = 1; msk < 16; msk <<= 1)
                tmax[v] = fmaxf(tmax[v], __shfl_xor(tmax[v], msk, 64));

        float scale[4], rsum[4];
#pragma unroll
        for (int v = 0; v < 4; ++v){
            float mn = fmaxf(m_run[v], tmax[v]);
            scale[v] = __expf(m_run[v] - mn);
            m_run[v] = mn;
            rsum[v] = 0.f;
        }
#pragma unroll
        for (int n = 0; n < 4; ++n)
#pragma unroll
            for (int v = 0; v < 4; ++v){
                float e = __expf(p[n][v] - m_run[v]);
                p[n][v] = e;
                rsum[v] += e;
            }
#pragma unroll
        for (int v = 0; v < 4; ++v){
#pragma unroll
            for (int msk = 1; msk < 16; msk <<= 1)
                rsum[v] += __shfl_xor(rsum[v], msk, 64);
            l_run[v] = l_run[v]*scale[v] + rsum[v];
        }
#pragma unroll
        for (int n = 0; n < 4; ++n)
#pragma unroll
            for (int v = 0; v < 4; ++v) acc_o[n][v] *= scale[v];

        // P (D-layout) -> per-wave LDS -> A-frag layout
#pragma unroll
        for (int n = 0; n < 4; ++n)
#pragma unroll
            for (int v = 0; v < 4; ++v)
                Ps[wid][(lg*4 + v)*72 + 16*n + lr] = f2bf(p[n][v]);
        asm volatile("s_waitcnt lgkmcnt(0)" ::: "memory");

        s16x8 pa0 = *(const s16x8*)&Ps[wid][lr*72 + lg*8];
        s16x8 pa1 = *(const s16x8*)&Ps[wid][lr*72 + 32 + lg*8];
#pragma unroll
        for (int n = 0; n < 4; ++n){
            s16x8 bv0 = frag(vt_s, 16*n + lr, lg);      // keys 0..31
            s16x8 bv1 = frag(vt_s, 16*n + lr, 4 + lg);  // keys 32..63
            acc_o[n] = MFMA16(pa0, bv0, acc_o[n]);
            acc_o[n] = MFMA16(pa1, bv1, acc_o[n]);
        }
    }

    // store partial: 64 rows x 64 d bf16 + (m,l) f32 per row
    short* ab = (j < 512) ? acc0 + (size_t)j*4096
              : (j < 768) ? acc1 + (size_t)(j-512)*4096
                          : acc2 + (size_t)(j-768)*4096;
#pragma unroll
    for (int n = 0; n < 4; ++n)
#pragma unroll
        for (int v = 0; v < 4; ++v)
            ab[(wid*16 + lg*4 + v)*64 + 16*n + lr] = f2bf(acc_o[n][v]);
    if (lr == 0){
#pragma unroll
        for (int v = 0; v < 4; ++v){
            ML[((size_t)j*64 + wid*16 + lg*4 + v)*2 + 0] = m_run[v];
            ML[((size_t)j*64 + wid*16 + lg*4 + v)*2 + 1] = l_run[v];
        }
    }
}

// ---------------- merge partials + analytic tail -> O bf16 [s][1024] --------
__global__ __launch_bounds__(256)
void attn_merge(const short* __restrict__ acc0, const short* __restrict__ acc1,
                const short* __restrict__ acc2, const float* __restrict__ ML,
                const float* __restrict__ SSV, short* __restrict__ O)
{
    const int b = blockIdx.x;          // 0..511
    const int h = b & 15, qst = b >> 4;
    const int d = threadIdx.x & 63, rg = threadIdx.x >> 6;
    const int C = (qst + 8) >> 3;      // ceil((qst+1)/8) chunks
    const int tbase = (qst < 8)  ? qst
                    : (qst < 16) ? 8  + 2*(qst - 8)
                    : (qst < 24) ? 24 + 3*(qst - 16)
                                 : 48 + 4*(qst - 24);
    const float F = (float)(S_LEN - 64*(qst + 1));
    const float svd = SSV[((size_t)h*33 + (qst + 1))*64 + d];

    for (int i = 0; i < 16; ++i){
        int r = rg + 4*i;              // 0..63
        float M = -1e30f;
        for (int c = 0; c < C; ++c){
            int job = (tbase + c)*16 + h;
            M = fmaxf(M, ML[((size_t)job*64 + r)*2]);
        }
        float num = 0.f, den = 0.f;
        for (int c = 0; c < C; ++c){
            int job = (tbase + c)*16 + h;
            float m = ML[((size_t)job*64 + r)*2];
            float l = ML[((size_t)job*64 + r)*2 + 1];
            const short* ab = (job < 512) ? acc0 + (size_t)job*4096
                            : (job < 768) ? acc1 + (size_t)(job-512)*4096
                                          : acc2 + (size_t)(job-768)*4096;
            float e = __expf(m - M);
            num += e * bf2f(ab[r*64 + d]);
            den += e * l;
        }
        float et = __expf(CMASK - M);
        num += et * svd;
        den += et * F;
        O[(size_t)(qst*64 + r)*DM + h*64 + d] = f2bf(num/den);
    }
}

extern "C" void kernel_launch(void* const* d_in, const int* in_sizes, int n_in,
                              void* d_out, int out_size, void* d_ws, size_t ws_size,
                              hipStream_t stream)
{
    (void)in_sizes; (void)n_in; (void)out_size; (void)ws_size;
    const float* hs   = (const float*)d_in[0];
    const float* wqkv = (const float*)d_in[1];
    const float* bqkv = (const float*)d_in[2];
    const float* wprj = (const float*)d_in[3];
    const float* bprj = (const float*)d_in[4];

    char* p = (char*)d_ws;                        // ~39.7 MiB used
    short* Ahg  = (short*)(p + (0ull  << 20));    // 4 MiB  (-> O after attn)
    short* Alg  = (short*)(p + (4ull  << 20));    // 4 MiB  (-> acc seg0: jobs 0..511)
    short* WqTh = (short*)(p + (8ull  << 20));    // 6 MiB  (-> WpT)
    short* WqTl = (short*)(p + (14ull << 20));    // 2 MiB  (-> acc seg1: jobs 512..767)
    short* QHh  = (short*)(p + (16ull << 20));    // 4 MiB (head-major)
    short* QHl  = (short*)(p + (20ull << 20));    // 4 MiB
    short* KH   = (short*)(p + (24ull << 20));    // 4 MiB (head-major)
    short* Vbg  = (short*)(p + (28ull << 20));    // 4 MiB (-> acc seg2: jobs 768..1279)
    short* VT   = (short*)(p + (32ull << 20));    // 4.07 MiB, ends ~36.06 MiB
    float* PB   = (float*)(p + (38ull << 20));                     // 128 KiB
    float* SSV  = (float*)(p + (38ull << 20) + (256ull << 10));    // 132 KiB
    float* ML   = (float*)(p + (39ull << 20));                     // 640 KiB
    short* O    = Ahg;
    short* WpT  = WqTh;

    split_f32<<<S_LEN*DM/4/256, 256, 0, stream>>>(hs, Ahg, Alg, S_LEN*DM/4);
    wtrans<true><<<dim3(3*DM/64, DM/64), 256, 0, stream>>>(wqkv, 3*DM, WqTh, WqTl);

    gemm_qkv<<<dim3(24, 16), 256, 0, stream>>>(
        Ahg, Alg, WqTh, WqTl, bqkv, QHh, QHl, KH, Vbg);

    wtrans<false><<<dim3(DM/64, DM/64), 256, 0, stream>>>(wprj, DM, WpT, nullptr);
    vtrans<<<dim3(DM/64, S_LEN/64), 256, 0, stream>>>(Vbg, VT);
    sv_partial<<<dim3(32, NH), 64, 0, stream>>>(Vbg, PB);
    sv_suffix<<<NH, 64, 0, stream>>>(PB, SSV);

    attn_fwd<<<1280, 256, 0, stream>>>(QHh, QHl, KH, VT, Alg, WqTl, Vbg, ML);
    attn_merge<<<512, 256, 0, stream>>>(Alg, WqTl, Vbg, ML, SSV, O);

    gemm_proj<<<dim3(8, 16), 256, 0, stream>>>(O, WpT, bprj, (float*)d_out);
}